// Round 3
// baseline (310.704 us; speedup 1.0000x reference)
//
#include <hip/hip_runtime.h>

// Problem constants
#define BATCH 4096
#define INF   2048
#define OUTF  2048

typedef __attribute__((ext_vector_type(8))) short bf16x8;
typedef __attribute__((ext_vector_type(4))) float f32x4;

// float -> bf16 bits, round-to-nearest-even
__device__ inline unsigned short f2bf(float f) {
  unsigned int u = __float_as_uint(f);
  u += 0x7fffu + ((u >> 16) & 1u);
  return (unsigned short)(u >> 16);
}

// 16B async global->LDS. LDS dest is wave-uniform base; HW writes base + lane*16.
__device__ inline void gld16(const void* g, void* l) {
  __builtin_amdgcn_global_load_lds(
      (const __attribute__((address_space(1))) void*)g,
      (__attribute__((address_space(3))) void*)l,
      16, 0, 0);
}

// Fused pack: x_re,x_im (4096x2048) and w_re,w_im (2048x2048) fp32 -> bf16,
// plain row-major.
__global__ __launch_bounds__(256) void pack_all(const float* __restrict__ xr,
                                                const float* __restrict__ xi,
                                                const float* __restrict__ wr,
                                                const float* __restrict__ wi,
                                                unsigned short* __restrict__ Xre,
                                                unsigned short* __restrict__ Xim,
                                                unsigned short* __restrict__ Wr,
                                                unsigned short* __restrict__ Wi) {
  const int XCH = (BATCH * INF) / 8;   // 1048576 ushort8 chunks for each x matrix
  int t = blockIdx.x * 256 + threadIdx.x;
  const float4 *s0, *s1;
  bf16x8 *d0, *d1;
  int idx;
  if (t < XCH) {
    idx = t;
    s0 = (const float4*)xr; s1 = (const float4*)xi;
    d0 = (bf16x8*)Xre;      d1 = (bf16x8*)Xim;
  } else {
    idx = t - XCH;                      // < (OUTF*INF)/8 = 524288
    s0 = (const float4*)wr; s1 = (const float4*)wi;
    d0 = (bf16x8*)Wr;       d1 = (bf16x8*)Wi;
  }
  float4 a0 = s0[2 * idx], a1 = s0[2 * idx + 1];
  float4 b0 = s1[2 * idx], b1 = s1[2 * idx + 1];
  bf16x8 v0, v1;
  v0[0] = (short)f2bf(a0.x); v0[1] = (short)f2bf(a0.y);
  v0[2] = (short)f2bf(a0.z); v0[3] = (short)f2bf(a0.w);
  v0[4] = (short)f2bf(a1.x); v0[5] = (short)f2bf(a1.y);
  v0[6] = (short)f2bf(a1.z); v0[7] = (short)f2bf(a1.w);
  v1[0] = (short)f2bf(b0.x); v1[1] = (short)f2bf(b0.y);
  v1[2] = (short)f2bf(b0.z); v1[3] = (short)f2bf(b0.w);
  v1[4] = (short)f2bf(b1.x); v1[5] = (short)f2bf(b1.y);
  v1[6] = (short)f2bf(b1.z); v1[7] = (short)f2bf(b1.w);
  d0[idx] = v0;
  d1[idx] = v1;
}

// Fused complex GEMM over K=2048.
// out[b,o,0] = Xre.Wr^T - Xim.Wi^T ; out[b,o,1] = Xre.Wi^T + Xim.Wr^T
// 128x128 block tile, 4 waves (2x2), each 64x64 via 4x4 mfma 16x16x32 bf16.
//
// Round-3 change vs the 123.5us baseline: X fragments are loaded DIRECTLY from
// global to registers (MFMA A-layout: lane reads 16B at row lrow, chunk lhi ->
// 16 rows x 64B segments, L1/L2-served). Only W is staged through LDS (exact
// baseline scheme: single buffer, chunk-swizzled, 8 gld16/thread per BK=64).
// This halves LDS-pipe load (reads 32->16 b128/wave/kt, writes 64->32KB/blk/kt)
// and halves the barrier-drained stage queue. X h0 loads issue before the top
// barrier (latency shared with the W-stage drain); X h1 loads issue before the
// h0 MFMA cluster (~310cy cover). LDS = 32KB -> still 2 blocks/CU.
// XCD-aware bijective swizzle: each XCD owns 4 consecutive bm panels (4MB of X
// = its private L2), so direct X re-reads are L2-local.
__global__ __launch_bounds__(256, 2) void cgemm(const unsigned short* __restrict__ Xre,
                                                const unsigned short* __restrict__ Xim,
                                                const unsigned short* __restrict__ Wr,
                                                const unsigned short* __restrict__ Wi,
                                                float* __restrict__ out) {
  __shared__ unsigned short sWr[128 * 64];  // 16 KB
  __shared__ unsigned short sWi[128 * 64];  // 16 KB

  const int tid  = threadIdx.x;
  const int wid  = tid >> 6;
  const int lane = tid & 63;
  const int lrow = lane & 15;
  const int lhi  = lane >> 4;
  const int wm   = wid >> 1;
  const int wn   = wid & 1;

  // XCD-aware bijective remap: 512 blocks, 8 XCDs, 64 blocks per XCD covering
  // bm panels [xcd*4, xcd*4+4) x all 16 bn tiles.
  const int wg  = blockIdx.y * 16 + blockIdx.x;   // grid (16,32)
  const int s   = (wg & 7) * 64 + (wg >> 3);      // bijective (512 % 8 == 0)
  const int bn0 = (s & 15) * 128;                 // out-feature tile
  const int bm0 = (s >> 4) * 128;                 // batch tile

  // W staging map (unchanged from baseline): thread t -> row tid>>2, chunk
  // tid&3, source column chunk swizzled: LDS(r,c) holds global chunk c^s(r),
  // s(r) = (r&3)^((r>>2)&3).
  const int srow = tid >> 2;                        // 0..63 (+64 for 2nd gld)
  const int sc   = tid & 3;
  const int ss   = (srow & 3) ^ ((srow >> 2) & 3);  // same for srow and srow+64
  const int scol = (sc ^ ss) * 8;                   // shorts within 32-wide half

  const unsigned short* gWr = Wr + (size_t)(bn0 + srow) * INF + scol;
  const unsigned short* gWi = Wi + (size_t)(bn0 + srow) * INF + scol;
  const int ldsoff = wid * 1024;   // bytes; + h*8192, +4096 for rows 64..127

  // W fragment read swizzle: logical k-chunk lhi -> LDS chunk lhi^s(row).
  const int slane  = (lrow & 3) ^ ((lrow >> 2) & 3);
  const int kchunk = (lhi ^ slane) * 8;             // shorts

  // X direct-load per-lane base pointers (MFMA A-fragment layout).
  const unsigned short* pXre = Xre + (size_t)(bm0 + wm * 64 + lrow) * INF + lhi * 8;
  const unsigned short* pXim = Xim + (size_t)(bm0 + wm * 64 + lrow) * INF + lhi * 8;

  f32x4 accre[4][4], accim[4][4];
  const f32x4 zz = {0.f, 0.f, 0.f, 0.f};
#pragma unroll
  for (int i = 0; i < 4; ++i)
#pragma unroll
    for (int j = 0; j < 4; ++j) { accre[i][j] = zz; accim[i][j] = zz; }

  const bf16x8 SGN = {(short)0x8000, (short)0x8000, (short)0x8000, (short)0x8000,
                      (short)0x8000, (short)0x8000, (short)0x8000, (short)0x8000};

  for (int kt = 0; kt < INF; kt += 64) {
    // ---- stage W for this K-step (8 gld16, single-buffered) ----
#pragma unroll
    for (int h = 0; h < 2; ++h) {
      const int go = kt + h * 32;
      const int lo = h * 8192 + ldsoff;
      gld16(gWr + go,                    (char*)sWr + lo);
      gld16(gWr + go + (size_t)64 * INF, (char*)sWr + lo + 4096);
      gld16(gWi + go,                    (char*)sWi + lo);
      gld16(gWi + go + (size_t)64 * INF, (char*)sWi + lo + 4096);
    }
    // ---- issue X h=0 register loads; latency shared with W-stage drain ----
    bf16x8 xr0[4], xi0[4];
#pragma unroll
    for (int i = 0; i < 4; ++i) {
      xr0[i] = *(const bf16x8*)&pXre[(size_t)i * 16 * INF + kt];
      xi0[i] = *(const bf16x8*)&pXim[(size_t)i * 16 * INF + kt];
    }
    __syncthreads();   // drains W gld16 (and X h0) via vmcnt(0)

    // ---- h = 0: W frags from LDS, issue X h=1, 64 MFMA ----
    bf16x8 wr_[4], wi_[4], wn_[4];
#pragma unroll
    for (int j = 0; j < 4; ++j) {
      wr_[j] = *(const bf16x8*)&sWr[(wn * 64 + j * 16 + lrow) * 32 + kchunk];
      wi_[j] = *(const bf16x8*)&sWi[(wn * 64 + j * 16 + lrow) * 32 + kchunk];
      wn_[j] = wi_[j] ^ SGN;   // -w_im
    }
    bf16x8 xr1[4], xi1[4];
#pragma unroll
    for (int i = 0; i < 4; ++i) {
      xr1[i] = *(const bf16x8*)&pXre[(size_t)i * 16 * INF + kt + 32];
      xi1[i] = *(const bf16x8*)&pXim[(size_t)i * 16 * INF + kt + 32];
    }
#pragma unroll
    for (int i = 0; i < 4; ++i)
#pragma unroll
      for (int j = 0; j < 4; ++j) {
        accre[i][j] = __builtin_amdgcn_mfma_f32_16x16x32_bf16(xr0[i], wr_[j], accre[i][j], 0, 0, 0);
        accre[i][j] = __builtin_amdgcn_mfma_f32_16x16x32_bf16(xi0[i], wn_[j], accre[i][j], 0, 0, 0);
        accim[i][j] = __builtin_amdgcn_mfma_f32_16x16x32_bf16(xr0[i], wi_[j], accim[i][j], 0, 0, 0);
        accim[i][j] = __builtin_amdgcn_mfma_f32_16x16x32_bf16(xi0[i], wr_[j], accim[i][j], 0, 0, 0);
      }

    // ---- h = 1: W frags from LDS, 64 MFMA (X h1 loads drained by use) ----
#pragma unroll
    for (int j = 0; j < 4; ++j) {
      wr_[j] = *(const bf16x8*)&sWr[4096 + (wn * 64 + j * 16 + lrow) * 32 + kchunk];
      wi_[j] = *(const bf16x8*)&sWi[4096 + (wn * 64 + j * 16 + lrow) * 32 + kchunk];
      wn_[j] = wi_[j] ^ SGN;
    }
#pragma unroll
    for (int i = 0; i < 4; ++i)
#pragma unroll
      for (int j = 0; j < 4; ++j) {
        accre[i][j] = __builtin_amdgcn_mfma_f32_16x16x32_bf16(xr1[i], wr_[j], accre[i][j], 0, 0, 0);
        accre[i][j] = __builtin_amdgcn_mfma_f32_16x16x32_bf16(xi1[i], wn_[j], accre[i][j], 0, 0, 0);
        accim[i][j] = __builtin_amdgcn_mfma_f32_16x16x32_bf16(xr1[i], wi_[j], accim[i][j], 0, 0, 0);
        accim[i][j] = __builtin_amdgcn_mfma_f32_16x16x32_bf16(xi1[i], wr_[j], accim[i][j], 0, 0, 0);
      }
    __syncthreads();   // protect next K-step's W overwrite
  }

  // Epilogue: C/D layout col=lane&15, row=(lane>>4)*4+reg. Interleaved {re,im}.
  const int row0 = bm0 + wm * 64 + lhi * 4;
  const int col0 = bn0 + wn * 64 + lrow;
#pragma unroll
  for (int i = 0; i < 4; ++i)
#pragma unroll
    for (int j = 0; j < 4; ++j)
#pragma unroll
      for (int r = 0; r < 4; ++r) {
        int row = row0 + i * 16 + r;
        int col = col0 + j * 16;
        float2 v = make_float2(accre[i][j][r], accim[i][j][r]);
        *(float2*)&out[((size_t)row * OUTF + col) * 2] = v;
      }
}

// Safety fallback if workspace too small: fp32 vector path (slow but correct)
__global__ __launch_bounds__(256) void naive_cx(const float* __restrict__ xr,
                                                const float* __restrict__ xi,
                                                const float* __restrict__ wr,
                                                const float* __restrict__ wi,
                                                float* __restrict__ out) {
  int t = blockIdx.x * 256 + threadIdx.x;
  int b = t >> 11, o = t & 2047;
  const float* xrb = xr + (size_t)b * INF;
  const float* xib = xi + (size_t)b * INF;
  const float* wrb = wr + (size_t)o * INF;
  const float* wib = wi + (size_t)o * INF;
  float are = 0.f, aim = 0.f;
  for (int i = 0; i < INF; ++i) {
    float a = xrb[i], c = xib[i], p = wrb[i], q = wib[i];
    are += a * p - c * q;
    aim += a * q + c * p;
  }
  out[(size_t)t * 2 + 0] = are;
  out[(size_t)t * 2 + 1] = aim;
}

extern "C" void kernel_launch(void* const* d_in, const int* in_sizes, int n_in,
                              void* d_out, int out_size, void* d_ws, size_t ws_size,
                              hipStream_t stream) {
  const float* xr = (const float*)d_in[0];
  const float* xi = (const float*)d_in[1];
  const float* wr = (const float*)d_in[2];
  const float* wi = (const float*)d_in[3];
  float* out = (float*)d_out;

  const size_t nx = (size_t)BATCH * INF;   // 8M elements per x matrix
  const size_t nw = (size_t)OUTF * INF;    // 4M elements per w matrix
  const size_t need = (2 * nx + 2 * nw) * sizeof(unsigned short);  // 48 MiB

  if (ws_size < need) {
    naive_cx<<<(BATCH * OUTF) / 256, 256, 0, stream>>>(xr, xi, wr, wi, out);
    return;
  }

  unsigned short* Xre = (unsigned short*)d_ws;
  unsigned short* Xim = Xre + nx;
  unsigned short* Wr  = Xim + nx;
  unsigned short* Wi  = Wr + nw;

  // pack_all: one thread per ushort8 chunk of each (re,im) pair
  const int grid_pack = (int)((nx / 8 + nw / 8) / 256);           // 6144
  pack_all<<<grid_pack, 256, 0, stream>>>(xr, xi, wr, wi, Xre, Xim, Wr, Wi);

  dim3 grid(OUTF / 128, BATCH / 128);   // 16 x 32 = 512 blocks
  cgemm<<<grid, 256, 0, stream>>>(Xre, Xim, Wr, Wi, out);
}

// Round 5
// 280.225 us; speedup vs baseline: 1.1088x; 1.1088x over previous
//
#include <hip/hip_runtime.h>

// Problem constants
#define BATCH 4096
#define INF   2048
#define OUTF  2048

typedef __attribute__((ext_vector_type(8))) short bf16x8;
typedef __attribute__((ext_vector_type(4))) float f32x4;

// float -> bf16 bits, round-to-nearest-even
__device__ inline unsigned short f2bf(float f) {
  unsigned int u = __float_as_uint(f);
  u += 0x7fffu + ((u >> 16) & 1u);
  return (unsigned short)(u >> 16);
}

// 16B async global->LDS. LDS dest is wave-uniform base; HW writes base + lane*16.
__device__ inline void gld16(const void* g, void* l) {
  __builtin_amdgcn_global_load_lds(
      (const __attribute__((address_space(1))) void*)g,
      (__attribute__((address_space(3))) void*)l,
      16, 0, 0);
}

// Fused pack: x_re,x_im (4096x2048) and w_re,w_im (2048x2048) fp32 -> bf16,
// plain row-major.
__global__ __launch_bounds__(256) void pack_all(const float* __restrict__ xr,
                                                const float* __restrict__ xi,
                                                const float* __restrict__ wr,
                                                const float* __restrict__ wi,
                                                unsigned short* __restrict__ Xre,
                                                unsigned short* __restrict__ Xim,
                                                unsigned short* __restrict__ Wr,
                                                unsigned short* __restrict__ Wi) {
  const int XCH = (BATCH * INF) / 8;   // 1048576 ushort8 chunks for each x matrix
  int t = blockIdx.x * 256 + threadIdx.x;
  const float4 *s0, *s1;
  bf16x8 *d0, *d1;
  int idx;
  if (t < XCH) {
    idx = t;
    s0 = (const float4*)xr; s1 = (const float4*)xi;
    d0 = (bf16x8*)Xre;      d1 = (bf16x8*)Xim;
  } else {
    idx = t - XCH;                      // < (OUTF*INF)/8 = 524288
    s0 = (const float4*)wr; s1 = (const float4*)wi;
    d0 = (bf16x8*)Wr;       d1 = (bf16x8*)Wi;
  }
  float4 a0 = s0[2 * idx], a1 = s0[2 * idx + 1];
  float4 b0 = s1[2 * idx], b1 = s1[2 * idx + 1];
  bf16x8 v0, v1;
  v0[0] = (short)f2bf(a0.x); v0[1] = (short)f2bf(a0.y);
  v0[2] = (short)f2bf(a0.z); v0[3] = (short)f2bf(a0.w);
  v0[4] = (short)f2bf(a1.x); v0[5] = (short)f2bf(a1.y);
  v0[6] = (short)f2bf(a1.z); v0[7] = (short)f2bf(a1.w);
  v1[0] = (short)f2bf(b0.x); v1[1] = (short)f2bf(b0.y);
  v1[2] = (short)f2bf(b0.z); v1[3] = (short)f2bf(b0.w);
  v1[4] = (short)f2bf(b1.x); v1[5] = (short)f2bf(b1.y);
  v1[6] = (short)f2bf(b1.z); v1[7] = (short)f2bf(b1.w);
  d0[idx] = v0;
  d1[idx] = v1;
}

// Fused complex GEMM over K=2048.
// out[b,o,0] = Xre.Wr^T - Xim.Wi^T ; out[b,o,1] = Xre.Wi^T + Xim.Wr^T
// 128x128 block tile, 4 waves (2x2), each 64x64 via 4x4 mfma 16x16x32 bf16.
//
// Round-5 = round-4 resubmitted (bench infra failed; kernel cannot deadlock:
// zero barriers, bounds audited).
// Structure: WAVE-PRIVATE staging, ZERO barriers. Each wave owns a 16 KB LDS
// region holding its own 64 X rows (re,im) and 64 W rows (r,i) for one BK=32
// K-step. Sync is per-wave s_waitcnt only (vmcnt counters are per-wave), so
// the 8 waves/CU drift freely instead of stalling in lockstep at block
// barriers. Pipeline per K-step (registers are the 2nd buffer):
//   vmcnt(0)            -- this wave's 16 staged loads landed
//   16x ds_read_b128    -- all frags to VGPR
//   lgkmcnt(0)          -- frags in regs -> buffer dead (WAR safe)
//   issue 16x gld16 for kt+32 (overwrites same private buffer)
//   64 MFMA             -- covers the staging latency
// Cost: wave pairs no longer share panels -> 2x staging traffic (L1/L2-hit
// duplicates). LDS chunk swizzle identical to baseline: LDS(r,c) holds global
// chunk c^s(r), s(r)=(r&3)^((r>>2)&3); frag k-chunk lhi -> lhi^s(row).
__global__ __launch_bounds__(256, 2) void cgemm(const unsigned short* __restrict__ Xre,
                                                const unsigned short* __restrict__ Xim,
                                                const unsigned short* __restrict__ Wr,
                                                const unsigned short* __restrict__ Wi,
                                                float* __restrict__ out) {
  // 4 waves x 8192 shorts (16 KB): [0,2048)=Xre, [2048,4096)=Xim,
  // [4096,6144)=Wr, [6144,8192)=Wi. Each region: 64 rows x 32 shorts.
  __shared__ unsigned short lds[4 * 8192];   // 64 KB -> 2 blocks/CU

  const int tid  = threadIdx.x;
  const int wid  = tid >> 6;
  const int lane = tid & 63;
  const int lrow = lane & 15;
  const int lhi  = lane >> 4;
  const int wm   = wid >> 1;
  const int wn   = wid & 1;

  const int bn0 = blockIdx.x * 128;   // out-feature tile
  const int bm0 = blockIdx.y * 128;   // batch tile

  unsigned short* wlds = lds + wid * 8192;   // wave-private base

  // Staging map (per gld16 instr r): lane l writes LDS bytes base+l*16 ->
  // row r*16 + (l>>2), chunk l&3. Source column chunk pre-swizzled:
  // LDS(row,c) holds global chunk c^s(row), s(row)=(row&3)^((row>>2)&3)
  // (s is invariant under row += 16, so one scol works for all 4 instrs).
  const int srow = lane >> 2;                       // 0..15
  const int sc   = lane & 3;
  const int ss   = (srow & 3) ^ ((srow >> 2) & 3);
  const int scol = (sc ^ ss) * 8;                   // shorts

  const unsigned short* gXre = Xre + (size_t)(bm0 + wm * 64 + srow) * INF + scol;
  const unsigned short* gXim = Xim + (size_t)(bm0 + wm * 64 + srow) * INF + scol;
  const unsigned short* gWr  = Wr  + (size_t)(bn0 + wn * 64 + srow) * INF + scol;
  const unsigned short* gWi  = Wi  + (size_t)(bn0 + wn * 64 + srow) * INF + scol;

  // Fragment read: logical k-chunk lhi -> LDS chunk lhi^s(row); s(row)==slane
  // for row = i*16+lrow (multiples of 16 drop out of s()).
  const int slane  = (lrow & 3) ^ ((lrow >> 2) & 3);
  const int kchunk = (lhi ^ slane) * 8;             // shorts

  f32x4 accre[4][4], accim[4][4];
  const f32x4 zz = {0.f, 0.f, 0.f, 0.f};
#pragma unroll
  for (int i = 0; i < 4; ++i)
#pragma unroll
    for (int j = 0; j < 4; ++j) { accre[i][j] = zz; accim[i][j] = zz; }

  const bf16x8 SGN = {(short)0x8000, (short)0x8000, (short)0x8000, (short)0x8000,
                      (short)0x8000, (short)0x8000, (short)0x8000, (short)0x8000};

  // 16 gld16: stage this wave's 4 matrices for k-chunk [kt, kt+32).
  auto STAGE = [&](int kt) {
#pragma unroll
    for (int r = 0; r < 4; ++r) {
      const size_t go = (size_t)r * 16 * INF + kt;        // rows r*16..r*16+15
      gld16(gXre + go, (char*)wlds + r * 1024);
      gld16(gXim + go, (char*)wlds + 4096 + r * 1024);
      gld16(gWr  + go, (char*)wlds + 8192 + r * 1024);
      gld16(gWi  + go, (char*)wlds + 12288 + r * 1024);
    }
  };

  STAGE(0);
#pragma unroll 1
  for (int kt = 0; kt < INF; kt += 32) {
    // This wave's staged loads have landed (per-wave counter; no barrier).
    asm volatile("s_waitcnt vmcnt(0)" ::: "memory");
    bf16x8 xr_[4], xi_[4], wr_[4], wi_[4], wn_[4];
#pragma unroll
    for (int i = 0; i < 4; ++i) {
      const int ro = (i * 16 + lrow) * 32 + kchunk;
      xr_[i] = *(const bf16x8*)&wlds[ro];
      xi_[i] = *(const bf16x8*)&wlds[2048 + ro];
      wr_[i] = *(const bf16x8*)&wlds[4096 + ro];
      wi_[i] = *(const bf16x8*)&wlds[6144 + ro];
    }
    // Frags in registers -> private buffer is dead; safe to overwrite.
    asm volatile("s_waitcnt lgkmcnt(0)" ::: "memory");
    __builtin_amdgcn_sched_barrier(0);   // rule 18: pin reg consumers below
    if (kt + 32 < INF) STAGE(kt + 32);   // uniform branch; prefetch next step
    __builtin_amdgcn_sched_barrier(0);   // don't sink the stage below MFMAs
#pragma unroll
    for (int j = 0; j < 4; ++j) wn_[j] = wi_[j] ^ SGN;   // -w_im fragments
    __builtin_amdgcn_s_setprio(1);
#pragma unroll
    for (int i = 0; i < 4; ++i)
#pragma unroll
      for (int j = 0; j < 4; ++j) {
        accre[i][j] = __builtin_amdgcn_mfma_f32_16x16x32_bf16(xr_[i], wr_[j], accre[i][j], 0, 0, 0);
        accre[i][j] = __builtin_amdgcn_mfma_f32_16x16x32_bf16(xi_[i], wn_[j], accre[i][j], 0, 0, 0);
        accim[i][j] = __builtin_amdgcn_mfma_f32_16x16x32_bf16(xr_[i], wi_[j], accim[i][j], 0, 0, 0);
        accim[i][j] = __builtin_amdgcn_mfma_f32_16x16x32_bf16(xi_[i], wr_[j], accim[i][j], 0, 0, 0);
      }
    __builtin_amdgcn_s_setprio(0);
  }

  // Epilogue: C/D layout col=lane&15, row=(lane>>4)*4+reg. Interleaved {re,im}.
  const int row0 = bm0 + wm * 64 + lhi * 4;
  const int col0 = bn0 + wn * 64 + lrow;
#pragma unroll
  for (int i = 0; i < 4; ++i)
#pragma unroll
    for (int j = 0; j < 4; ++j)
#pragma unroll
      for (int r = 0; r < 4; ++r) {
        int row = row0 + i * 16 + r;
        int col = col0 + j * 16;
        float2 v = make_float2(accre[i][j][r], accim[i][j][r]);
        *(float2*)&out[((size_t)row * OUTF + col) * 2] = v;
      }
}

// Safety fallback if workspace too small: fp32 vector path (slow but correct)
__global__ __launch_bounds__(256) void naive_cx(const float* __restrict__ xr,
                                                const float* __restrict__ xi,
                                                const float* __restrict__ wr,
                                                const float* __restrict__ wi,
                                                float* __restrict__ out) {
  int t = blockIdx.x * 256 + threadIdx.x;
  int b = t >> 11, o = t & 2047;
  const float* xrb = xr + (size_t)b * INF;
  const float* xib = xi + (size_t)b * INF;
  const float* wrb = wr + (size_t)o * INF;
  const float* wib = wi + (size_t)o * INF;
  float are = 0.f, aim = 0.f;
  for (int i = 0; i < INF; ++i) {
    float a = xrb[i], c = xib[i], p = wrb[i], q = wib[i];
    are += a * p - c * q;
    aim += a * q + c * p;
  }
  out[(size_t)t * 2 + 0] = are;
  out[(size_t)t * 2 + 1] = aim;
}

extern "C" void kernel_launch(void* const* d_in, const int* in_sizes, int n_in,
                              void* d_out, int out_size, void* d_ws, size_t ws_size,
                              hipStream_t stream) {
  const float* xr = (const float*)d_in[0];
  const float* xi = (const float*)d_in[1];
  const float* wr = (const float*)d_in[2];
  const float* wi = (const float*)d_in[3];
  float* out = (float*)d_out;

  const size_t nx = (size_t)BATCH * INF;   // 8M elements per x matrix
  const size_t nw = (size_t)OUTF * INF;    // 4M elements per w matrix
  const size_t need = (2 * nx + 2 * nw) * sizeof(unsigned short);  // 48 MiB

  if (ws_size < need) {
    naive_cx<<<(BATCH * OUTF) / 256, 256, 0, stream>>>(xr, xi, wr, wi, out);
    return;
  }

  unsigned short* Xre = (unsigned short*)d_ws;
  unsigned short* Xim = Xre + nx;
  unsigned short* Wr  = Xim + nx;
  unsigned short* Wi  = Wr + nw;

  // pack_all: one thread per ushort8 chunk of each (re,im) pair
  const int grid_pack = (int)((nx / 8 + nw / 8) / 256);           // 6144
  pack_all<<<grid_pack, 256, 0, stream>>>(xr, xi, wr, wi, Xre, Xim, Wr, Wi);

  dim3 grid(OUTF / 128, BATCH / 128);   // 16 x 32 = 512 blocks
  cgemm<<<grid, 256, 0, stream>>>(Xre, Xim, Wr, Wi, out);
}

// Round 6
// 257.553 us; speedup vs baseline: 1.2064x; 1.0880x over previous
//
#include <hip/hip_runtime.h>

// Problem constants
#define BATCH 4096
#define INF   2048
#define OUTF  2048

typedef __attribute__((ext_vector_type(8))) short bf16x8;
typedef __attribute__((ext_vector_type(4))) float f32x4;

// float -> bf16 bits, round-to-nearest-even
__device__ inline unsigned short f2bf(float f) {
  unsigned int u = __float_as_uint(f);
  u += 0x7fffu + ((u >> 16) & 1u);
  return (unsigned short)(u >> 16);
}

// 16B async global->LDS. LDS dest is wave-uniform base; HW writes base + lane*16.
__device__ inline void gld16(const void* g, void* l) {
  __builtin_amdgcn_global_load_lds(
      (const __attribute__((address_space(1))) void*)g,
      (__attribute__((address_space(3))) void*)l,
      16, 0, 0);
}

// Fused pack: x_re,x_im (4096x2048) and w_re,w_im (2048x2048) fp32 -> bf16,
// plain row-major (no concatenation, no duplication).
__global__ __launch_bounds__(256) void pack_all(const float* __restrict__ xr,
                                                const float* __restrict__ xi,
                                                const float* __restrict__ wr,
                                                const float* __restrict__ wi,
                                                unsigned short* __restrict__ Xre,
                                                unsigned short* __restrict__ Xim,
                                                unsigned short* __restrict__ Wr,
                                                unsigned short* __restrict__ Wi) {
  const int XCH = (BATCH * INF) / 8;   // 1048576 ushort8 chunks for each x matrix
  int t = blockIdx.x * 256 + threadIdx.x;
  const float4 *s0, *s1;
  bf16x8 *d0, *d1;
  int idx;
  if (t < XCH) {
    idx = t;
    s0 = (const float4*)xr; s1 = (const float4*)xi;
    d0 = (bf16x8*)Xre;      d1 = (bf16x8*)Xim;
  } else {
    idx = t - XCH;                      // < (OUTF*INF)/8 = 524288
    s0 = (const float4*)wr; s1 = (const float4*)wi;
    d0 = (bf16x8*)Wr;       d1 = (bf16x8*)Wi;
  }
  float4 a0 = s0[2 * idx], a1 = s0[2 * idx + 1];
  float4 b0 = s1[2 * idx], b1 = s1[2 * idx + 1];
  bf16x8 v0, v1;
  v0[0] = (short)f2bf(a0.x); v0[1] = (short)f2bf(a0.y);
  v0[2] = (short)f2bf(a0.z); v0[3] = (short)f2bf(a0.w);
  v0[4] = (short)f2bf(a1.x); v0[5] = (short)f2bf(a1.y);
  v0[6] = (short)f2bf(a1.z); v0[7] = (short)f2bf(a1.w);
  v1[0] = (short)f2bf(b0.x); v1[1] = (short)f2bf(b0.y);
  v1[2] = (short)f2bf(b0.z); v1[3] = (short)f2bf(b0.w);
  v1[4] = (short)f2bf(b1.x); v1[5] = (short)f2bf(b1.y);
  v1[6] = (short)f2bf(b1.z); v1[7] = (short)f2bf(b1.w);
  d0[idx] = v0;
  d1[idx] = v1;
}

// Fused complex GEMM over K=2048 with 4 raw tiles.
// out[b,o,0] = Xre.Wr^T - Xim.Wi^T ; out[b,o,1] = Xre.Wi^T + Xim.Wr^T
// 128x128 block tile, 4 waves (2x2), each 64x64 via 4x4 mfma 16x16x32 bf16.
// BK=64 staged as two 32-wide halves inside one barrier pair (128 MFMA/barrier).
// LDS chunk swizzle: c_lds = c ^ s(row), s(row)=(row&3)^((row>>2)&3) -> 2-way banks.
//
// Round-6 change vs the 123.5us round-0 baseline (only change): XCD-aware
// bijective block remap. Dispatch round-robins wg%8 -> XCD; we remap so each
// XCD owns one 8bm x 8bn PATCH of the 32x16 tile grid (patches arranged 4x2).
// The XCD's 64 blocks are exactly its 64 resident block slots (32 CU x 2
// blocks/CU), walking K roughly in phase: per K-step the patch's slice is
// (8+8) panels x 128 rows x 64 cols x 2B x 2(re,im) ~= 512 KB -> fits the 4 MB
// per-XCD L2, so each K-slice is fetched once and hit 8x, instead of the
// default mapping streaming all 32 X panels through every XCD's L2.
__global__ __launch_bounds__(256, 2) void cgemm(const unsigned short* __restrict__ Xre,
                                                const unsigned short* __restrict__ Xim,
                                                const unsigned short* __restrict__ Wr,
                                                const unsigned short* __restrict__ Wi,
                                                float* __restrict__ out) {
  __shared__ unsigned short sXre[128 * 64];  // 16 KB each, 64 KB total
  __shared__ unsigned short sXim[128 * 64];
  __shared__ unsigned short sWr[128 * 64];
  __shared__ unsigned short sWi[128 * 64];

  const int tid  = threadIdx.x;
  const int wid  = tid >> 6;
  const int lane = tid & 63;
  const int lrow = lane & 15;
  const int lhi  = lane >> 4;
  const int wm   = wid >> 1;
  const int wn   = wid & 1;

  // XCD patch remap: wg in [0,512), xcd = wg&7 (dispatch round-robin),
  // o = wg>>3 in [0,64) is the ordinal within the XCD.
  // Patch (pm,pn) = (xcd>>1, xcd&1); within-patch (om,on) = (o>>3, o&7).
  // bm_tile = pm*8+om in [0,32); bn_tile = pn*8+on in [0,16). Bijective.
  const int wg  = blockIdx.y * 16 + blockIdx.x;   // grid (16,32)
  const int xcd = wg & 7;
  const int o   = wg >> 3;
  const int bm0 = (((xcd >> 1) << 3) + (o >> 3)) * 128;   // batch tile
  const int bn0 = (((xcd & 1) << 3) + (o & 7)) * 128;     // out-feature tile

  // Staging map: chunk ch = p*256+tid -> LDS(row=ch>>2, c=ch&3); source column
  // chunk swizzled so LDS(r,c) holds global chunk c^s(r).
  const int srow = tid >> 2;                        // 0..63 (p=0), +64 for p=1
  const int sc   = tid & 3;
  const int ss   = (srow & 3) ^ ((srow >> 2) & 3);  // same for srow and srow+64
  const int scol = (sc ^ ss) * 8;                   // shorts within 32-wide half

  const unsigned short* gXre = Xre + (size_t)(bm0 + srow) * INF + scol;
  const unsigned short* gXim = Xim + (size_t)(bm0 + srow) * INF + scol;
  const unsigned short* gWr  = Wr  + (size_t)(bn0 + srow) * INF + scol;
  const unsigned short* gWi  = Wi  + (size_t)(bn0 + srow) * INF + scol;

  const int ldsoff = wid * 1024;   // bytes; + p*4096 + h*8192

  // Fragment read: logical k-chunk lhi -> LDS chunk lhi^s(row); s(row)==slane
  // for row = wm*64+i*16+lrow (multiples of 16 drop out).
  const int slane  = (lrow & 3) ^ ((lrow >> 2) & 3);
  const int kchunk = (lhi ^ slane) * 8;             // shorts

  f32x4 accre[4][4], accim[4][4];
  const f32x4 zz = {0.f, 0.f, 0.f, 0.f};
#pragma unroll
  for (int i = 0; i < 4; ++i)
#pragma unroll
    for (int j = 0; j < 4; ++j) { accre[i][j] = zz; accim[i][j] = zz; }

  const bf16x8 SGN = {(short)0x8000, (short)0x8000, (short)0x8000, (short)0x8000,
                      (short)0x8000, (short)0x8000, (short)0x8000, (short)0x8000};

  for (int kt = 0; kt < INF; kt += 64) {
#pragma unroll
    for (int h = 0; h < 2; ++h) {
      const int go = kt + h * 32;
      const int lo = h * 8192 + ldsoff;
      gld16(gXre + go,                  (char*)sXre + lo);
      gld16(gXre + go + (size_t)64 * INF, (char*)sXre + lo + 4096);
      gld16(gXim + go,                  (char*)sXim + lo);
      gld16(gXim + go + (size_t)64 * INF, (char*)sXim + lo + 4096);
      gld16(gWr + go,                   (char*)sWr + lo);
      gld16(gWr + go + (size_t)64 * INF,  (char*)sWr + lo + 4096);
      gld16(gWi + go,                   (char*)sWi + lo);
      gld16(gWi + go + (size_t)64 * INF,  (char*)sWi + lo + 4096);
    }
    __syncthreads();

#pragma unroll
    for (int h = 0; h < 2; ++h) {
      const int hb = h * 4096;  // shorts
      bf16x8 xr_[4], xi_[4], wr_[4], wi_[4], wn_[4];
#pragma unroll
      for (int i = 0; i < 4; ++i) {
        xr_[i] = *(const bf16x8*)&sXre[hb + (wm * 64 + i * 16 + lrow) * 32 + kchunk];
        xi_[i] = *(const bf16x8*)&sXim[hb + (wm * 64 + i * 16 + lrow) * 32 + kchunk];
        wr_[i] = *(const bf16x8*)&sWr [hb + (wn * 64 + i * 16 + lrow) * 32 + kchunk];
        wi_[i] = *(const bf16x8*)&sWi [hb + (wn * 64 + i * 16 + lrow) * 32 + kchunk];
      }
#pragma unroll
      for (int j = 0; j < 4; ++j) wn_[j] = wi_[j] ^ SGN;   // -w_im fragments
#pragma unroll
      for (int i = 0; i < 4; ++i)
#pragma unroll
        for (int j = 0; j < 4; ++j) {
          accre[i][j] = __builtin_amdgcn_mfma_f32_16x16x32_bf16(xr_[i], wr_[j], accre[i][j], 0, 0, 0);
          accre[i][j] = __builtin_amdgcn_mfma_f32_16x16x32_bf16(xi_[i], wn_[j], accre[i][j], 0, 0, 0);
          accim[i][j] = __builtin_amdgcn_mfma_f32_16x16x32_bf16(xr_[i], wi_[j], accim[i][j], 0, 0, 0);
          accim[i][j] = __builtin_amdgcn_mfma_f32_16x16x32_bf16(xi_[i], wr_[j], accim[i][j], 0, 0, 0);
        }
    }
    __syncthreads();
  }

  // Epilogue: C/D layout col=lane&15, row=(lane>>4)*4+reg. Interleaved {re,im}.
  const int row0 = bm0 + wm * 64 + lhi * 4;
  const int col0 = bn0 + wn * 64 + lrow;
#pragma unroll
  for (int i = 0; i < 4; ++i)
#pragma unroll
    for (int j = 0; j < 4; ++j)
#pragma unroll
      for (int r = 0; r < 4; ++r) {
        int row = row0 + i * 16 + r;
        int col = col0 + j * 16;
        float2 v = make_float2(accre[i][j][r], accim[i][j][r]);
        *(float2*)&out[((size_t)row * OUTF + col) * 2] = v;
      }
}

// Safety fallback if workspace too small: fp32 vector path (slow but correct)
__global__ __launch_bounds__(256) void naive_cx(const float* __restrict__ xr,
                                                const float* __restrict__ xi,
                                                const float* __restrict__ wr,
                                                const float* __restrict__ wi,
                                                float* __restrict__ out) {
  int t = blockIdx.x * 256 + threadIdx.x;
  int b = t >> 11, o = t & 2047;
  const float* xrb = xr + (size_t)b * INF;
  const float* xib = xi + (size_t)b * INF;
  const float* wrb = wr + (size_t)o * INF;
  const float* wib = wi + (size_t)o * INF;
  float are = 0.f, aim = 0.f;
  for (int i = 0; i < INF; ++i) {
    float a = xrb[i], c = xib[i], p = wrb[i], q = wib[i];
    are += a * p - c * q;
    aim += a * q + c * p;
  }
  out[(size_t)t * 2 + 0] = are;
  out[(size_t)t * 2 + 1] = aim;
}

extern "C" void kernel_launch(void* const* d_in, const int* in_sizes, int n_in,
                              void* d_out, int out_size, void* d_ws, size_t ws_size,
                              hipStream_t stream) {
  const float* xr = (const float*)d_in[0];
  const float* xi = (const float*)d_in[1];
  const float* wr = (const float*)d_in[2];
  const float* wi = (const float*)d_in[3];
  float* out = (float*)d_out;

  const size_t nx = (size_t)BATCH * INF;   // 8M elements per x matrix
  const size_t nw = (size_t)OUTF * INF;    // 4M elements per w matrix
  const size_t need = (2 * nx + 2 * nw) * sizeof(unsigned short);  // 48 MiB

  if (ws_size < need) {
    naive_cx<<<(BATCH * OUTF) / 256, 256, 0, stream>>>(xr, xi, wr, wi, out);
    return;
  }

  unsigned short* Xre = (unsigned short*)d_ws;
  unsigned short* Xim = Xre + nx;
  unsigned short* Wr  = Xim + nx;
  unsigned short* Wi  = Wr + nw;

  // pack_all: one thread per ushort8 chunk of each (re,im) pair
  const int grid_pack = (int)((nx / 8 + nw / 8) / 256);           // 6144
  pack_all<<<grid_pack, 256, 0, stream>>>(xr, xi, wr, wi, Xre, Xim, Wr, Wi);

  dim3 grid(OUTF / 128, BATCH / 128);   // 16 x 32 = 512 blocks
  cgemm<<<grid, 256, 0, stream>>>(Xre, Xim, Wr, Wi, out);
}